// Round 13
// baseline (155.282 us; speedup 1.0000x reference)
//
#include <hip/hip_runtime.h>
#include <math.h>

#define NB   8
#define NCC  16384
#define HID  128

typedef __attribute__((ext_vector_type(8))) short short8;
typedef __attribute__((ext_vector_type(4))) float f32x4;

#define MFMA(a,b,c) __builtin_amdgcn_mfma_f32_16x16x32_bf16(a,b,c,0,0,0)

// ---- ws float offsets ----
#define WS_AABS   0
#define WS_BASE1  8
#define WS_BOUT   2056
#define WS_BSUMR  2120
#define WS_BSUMZ  2248
#define WS_BIHN   2376
#define WS_BHHN   2504
#define WS_W64    2632
#define WS_INTERF 3024
#define WS_FRAG   3152      // 61440 floats = 122880 bf16 frags (W1|W2|WIH|WHH)
#define WS_SD     64592     // 64*128
#define WS_AVGT   73808     // 16384 (plain store per chunk by kA)
#define WS_TS     90192     // 8*16384 raw sum(out^2) per (b,cell)
#define WS_FMEAN  221264    // 64*128
#define WS_PART2  230480    // 256*64
#define WS_FPART  246864    // 8*256*128 (unique writer per (b,chunk64))
#define WS_CO     771152    // 16384*64 f32 (unique writer per chunk64)
#define WS_PARTE  1819728   // 256 exp-sum partials
#define WS_PARTA  1819984   // 256 avgt-sum partials

__device__ __forceinline__ unsigned short f2b(float f) {
    unsigned int u = __float_as_uint(f);
    unsigned int r = (u + 0x7fffu + ((u >> 16) & 1u)) >> 16;
    return (unsigned short)r;
}
__device__ __forceinline__ float b2f(unsigned short us) {
    return __uint_as_float(((unsigned int)us) << 16);
}
__device__ __forceinline__ float sigm(float x) {
    return __builtin_amdgcn_rcpf(1.f + __expf(-x));
}
__device__ __forceinline__ float tanh_fast(float x) {
    return 1.f - 2.f * __builtin_amdgcn_rcpf(__expf(2.f * x) + 1.f);
}
__device__ __forceinline__ unsigned int cvtpk(float lo, float hi) {
    unsigned int r;
    asm volatile("v_cvt_pk_bf16_f32 %0, %1, %2" : "=v"(r) : "v"(lo), "v"(hi));
    return r;
}
__device__ __forceinline__ void stg(char* dst, int row, int cb, float4 u, float4 v) {
    uint4 pk = make_uint4(cvtpk(u.x, u.y), cvtpk(u.z, u.w),
                          cvtpk(v.x, v.y), cvtpk(v.z, v.w));
    *(uint4*)(dst + row * 256 + (cb ^ ((row & 7) << 4))) = pk;
}

// ---------------- prep: fragment pre-swizzle + (block 0) scalars ----------------
__global__ __launch_bounds__(1024) void kprep(
    const float* __restrict__ x, const float* __restrict__ noise,
    const float* __restrict__ amps,
    const float* __restrict__ eaW1, const float* __restrict__ eaB1,
    const float* __restrict__ egW1, const float* __restrict__ egB1,
    const float* __restrict__ eaW2, const float* __restrict__ eaB2,
    const float* __restrict__ egW2, const float* __restrict__ egB2,
    const float* __restrict__ gWih, const float* __restrict__ gWhh,
    const float* __restrict__ gbih, const float* __restrict__ gbhh,
    float* __restrict__ ws)
{
    int i = blockIdx.x * 1024 + threadIdx.x;
    if (i < 122880) {
        short* wsh = (short*)(ws + WS_FRAG);
        float v;
        if (i < 32768) {                       // W1: K=128, N=256 (a|g), KT=4
            int rel = i;
            int j = rel & 7, l = (rel >> 3) & 63, tk = rel >> 9;
            int kt = tk & 3, nt = tk >> 2;
            int n = nt * 16 + (l & 15), k = kt * 32 + ((l >> 4) << 3) + j;
            v = (n < 128) ? eaW1[n * 192 + 64 + k] : egW1[(n - 128) * 192 + 64 + k];
        } else if (i < 49152) {                // W2: K=256 ([A1|G1]), N=64, KT=8
            int rel = i - 32768;
            int j = rel & 7, l = (rel >> 3) & 63, tk = rel >> 9;
            int kt = tk & 7, nt = tk >> 3;
            int d = nt * 16 + (l & 15), k = kt * 32 + ((l >> 4) << 3) + j;
            v = (k < 128) ? eaW2[d * 128 + k] : -egW2[d * 128 + (k - 128)];
        } else if (i < 73728) {                // WIH: K=64, N=384, KT=2
            int rel = i - 49152;
            int j = rel & 7, l = (rel >> 3) & 63, tk = rel >> 9;
            int kt = tk & 1, nt = tk >> 1;
            int r = nt * 16 + (l & 15), k = kt * 32 + ((l >> 4) << 3) + j;
            v = gWih[r * 65 + k];
        } else {                               // WHH: K=128, N=384, KT=4
            int rel = i - 73728;
            int j = rel & 7, l = (rel >> 3) & 63, tk = rel >> 9;
            int kt = tk & 3, nt = tk >> 2;
            int r = nt * 16 + (l & 15), k = kt * 32 + ((l >> 4) << 3) + j;
            v = gWhh[r * 128 + k];
        }
        wsh[i] = (short)f2b(v);
    }
    if (blockIdx.x == 0) {
        __shared__ float xb[8][64];
        int t = threadIdx.x;
        if (t < 512) {
            int b = t >> 6, k = t & 63;
            xb[b][k] = x[k] + noise[b * 64 + k] * (0.05f * (float)(b + 1));
        }
        if (t == 0) {
            float s = 0.f;
            for (int b = 0; b < 8; b++) s += fabsf(amps[b]);
            s += 1e-8f;
            for (int b = 0; b < 8; b++) ws[WS_AABS + b] = fabsf(amps[b]) / s;
        }
        __syncthreads();
        for (int ii = t; ii < 2048; ii += 1024) {
            int b = ii >> 8, n = ii & 255;
            const float* Wp; float s;
            if (n < 128) { Wp = eaW1 + n * 192; s = eaB1[n]; }
            else         { Wp = egW1 + (n - 128) * 192; s = egB1[n - 128]; }
            for (int k = 0; k < 64; k++) s += xb[b & 7][k] * Wp[k];
            ws[WS_BASE1 + ii] = s;
        }
        if (t < 64) ws[WS_BOUT + t] = eaB2[t] - egB2[t];
        if (t < 128) {
            ws[WS_BSUMR + t] = gbih[t] + gbhh[t];
            ws[WS_BSUMZ + t] = gbih[128 + t] + gbhh[128 + t];
            ws[WS_BIHN + t]  = gbih[256 + t];
            ws[WS_BHHN + t]  = gbhh[256 + t];
        }
        if (t < 384) ws[WS_W64 + t] = gWih[t * 65 + 64];
    }
}

// ================= kA: L1 + L2, weights LDS-resident, 16 waves =================
__global__ __launch_bounds__(1024) void kA(
    const float* __restrict__ hiddens, float* __restrict__ newh,
    float* __restrict__ ws)
{
    __shared__ char  wlds[98304];       // W1L @0 (64KB), W2L @65536 (32KB)
    __shared__ char  hsb[64 * 256];     // bf16 [64][128] swizzled (16KB)
    __shared__ char  agb[64 * 512];     // bf16 [64][256] (32KB)
    __shared__ float ts_s[64];
    __shared__ float tsum_s[64];

    const int t    = threadIdx.x;
    const int lane = t & 63;
    const int w    = t >> 6;
    const int rg   = w >> 2;
    const int nq   = w & 3;
    const int col  = lane & 15;
    const int kq   = lane >> 4;
    const int r0   = rg * 16;
    const int n0   = blockIdx.x * 64;

    {
        const float4* src = (const float4*)(ws + WS_FRAG);
        float4* dst = (float4*)wlds;
#pragma unroll
        for (int p = 0; p < 6; p++) dst[p * 1024 + t] = src[p * 1024 + t];
    }
    const short8* W1F = (const short8*)wlds;
    const short8* W2F = (const short8*)(wlds + 65536);

    const float bo = ws[WS_BOUT + nq * 16 + col];
    float co_reg[4];
#pragma unroll
    for (int i = 0; i < 4; i++) co_reg[i] = 0.f;
    if (t < 64) tsum_s[t] = 0.f;

    const int flat = t * 8;
    const int srow = flat >> 7;
    const int scb  = (flat & 127) * 2;

    {
        const float* hs = hiddens + (size_t)n0 * HID;
        float4 a0 = *(const float4*)(hs + flat);
        float4 a1 = *(const float4*)(hs + flat + 4);
        stg(hsb, srow, scb, a0, a1);
    }
    float4 pfa0, pfa1;
    unsigned short* outu = (unsigned short*)newh;

    for (int b = 0; b < NB; ++b) {
        __syncthreads();  // bar0
        if (t < 64) {
            if (b > 0) {
                ws[WS_TS + (size_t)(b - 1) * NCC + n0 + t] = ts_s[t];
                tsum_s[t] += ts_s[t];
            }
            ts_s[t] = 0.f;
        }
        if (b < 7) {
            const float* hsn = hiddens + ((size_t)((b + 1) * NCC + n0)) * HID;
            pfa0 = *(const float4*)(hsn + flat);
            pfa1 = *(const float4*)(hsn + flat + 4);
        }

        // ---- L1 ----
        {
            short8 aH[4];
#pragma unroll
            for (int ks = 0; ks < 4; ks++) {
                int row = r0 + col;
                aH[ks] = *(const short8*)(hsb + row * 256 +
                           ((ks * 64 + (kq << 4)) ^ ((row & 7) << 4)));
            }
#pragma unroll
            for (int nti = 0; nti < 4; nti++) {
                int nt = nq * 4 + nti;
                f32x4 ac = {0.f, 0.f, 0.f, 0.f};
#pragma unroll
                for (int kt = 0; kt < 4; kt++)
                    ac = MFMA(aH[kt], W1F[(nt * 4 + kt) * 64 + lane], ac);
                int n = nt * 16 + col;
                float bs = ws[WS_BASE1 + b * 256 + n];
#pragma unroll
                for (int j = 0; j < 4; j++) {
                    int row = r0 + (kq << 2) + j;
                    float v = fmaxf(ac[j] + bs, 0.f);
                    *(unsigned short*)(agb + row * 512 +
                        ((n * 2) ^ ((row & 7) << 4))) = f2b(v);
                }
            }
        }
        __syncthreads();  // barA

        if (b < 7) stg(hsb, srow, scb, pfa0, pfa1);

        // ---- L2 ----
        {
            f32x4 ov = {0.f, 0.f, 0.f, 0.f};
#pragma unroll
            for (int kt = 0; kt < 8; kt++) {
                int kb = kt * 64 + (kq << 4);
                int ra = r0 + col;
                short8 a0 = *(const short8*)(agb + ra * 512 + (kb ^ ((ra & 7) << 4)));
                ov = MFMA(a0, W2F[(nq * 8 + kt) * 64 + lane], ov);
            }
            int d = nq * 16 + col;
            float aab = ws[WS_AABS + b];
#pragma unroll
            for (int j = 0; j < 4; j++) {
                int row = r0 + (kq << 2) + j;
                float v = ov[j] + bo;
                co_reg[j] += aab * v;
                outu[(size_t)(b * NCC + n0 + row) * 256 + 192 + d] = f2b(v);
                float sq = v * v;
                sq += __shfl_xor(sq, 1);
                sq += __shfl_xor(sq, 2);
                sq += __shfl_xor(sq, 4);
                sq += __shfl_xor(sq, 8);
                if (col == 0) atomicAdd(&ts_s[row], sq);
            }
        }
    }
    __syncthreads();
    if (t < 64) {
        ws[WS_TS + (size_t)7 * NCC + n0 + t] = ts_s[t];
        tsum_s[t] += ts_s[t];
        ws[WS_AVGT + n0 + t] = tsum_s[t] * (1.f / 512.f);
    }
    {
        int d = nq * 16 + col;
#pragma unroll
        for (int j = 0; j < 4; j++) {
            int row = r0 + (kq << 2) + j;
            ws[WS_CO + (size_t)(n0 + row) * 64 + d] = co_reg[j];
        }
    }
}

// ================= kB: GRU, 256 blocks x 64 cells, WHH in LDS, WIH from L2 ===
// 1024 thr (16 waves: rg(4) x hq(4), 2 h-groups per wave). LDS ~122KB -> 1 block/CU,
// 256 blocks = exactly one pass, weights staged once per CU.
__global__ __launch_bounds__(1024) void kB(
    const float* __restrict__ hiddens, float* __restrict__ newh,
    float* __restrict__ ws)
{
    __shared__ char  wl[98304];         // WHH (96KB)
    __shared__ char  hsb[64 * 256];     // bf16 [64][128] swizzled (16KB)
    __shared__ char  otb[64 * 128];     // bf16 [64][64]  swizzled (8KB)
    __shared__ float ts_s[64];
    __shared__ float fp4[4][128];

    const int t    = threadIdx.x;
    const int lane = t & 63;
    const int w    = t >> 6;            // 0..15
    const int rg   = w >> 2;            // 0..3 -> rows rg*16..+16
    const int hq   = w & 3;             // 0..3 -> h groups {hq*2, hq*2+1}
    const int col  = lane & 15;
    const int kq   = lane >> 4;
    const int r0   = rg * 16;
    const int chunk = blockIdx.x;       // 256 chunks of 64 cells
    const int n0   = chunk * 64;

    // stage WHH only: 96KB = 6144 float4 (starts at frag byte 147456)
    {
        const float4* src = (const float4*)(ws + WS_FRAG) + 9216;
        float4* dst = (float4*)wl;
#pragma unroll
        for (int p = 0; p < 6; p++) dst[p * 1024 + t] = src[p * 1024 + t];
    }
    const short8* WHHF = (const short8*)wl;
    const short8* WIHF = (const short8*)((const short*)(ws + WS_FRAG) + 49152); // L2
    const unsigned short* outu = (const unsigned short*)newh;

    const int flat = t * 8;             // 8192 floats = 64x128
    const int srow = flat >> 7;
    const int scb  = (flat & 127) * 2;
    const int ocell = t >> 4;           // 0..63
    const int ooff  = (t & 15) * 4;     // u16 offset 0..60

    // prologue: load branch 0 tiles into regs
    float4 rh0, rh1;
    uint2  ro;
    float  rts = 0.f;
    {
        const float* hs = hiddens + (size_t)n0 * HID;
        rh0 = *(const float4*)(hs + flat);
        rh1 = *(const float4*)(hs + flat + 4);
        ro  = *(const uint2*)(outu + (size_t)(n0 + ocell) * 256 + 192 + ooff);
    }
    if (t < 64) rts = ws[WS_TS + n0 + t];

    for (int b = 0; b < NB; ++b) {
        stg(hsb, srow, scb, rh0, rh1);
        *(uint2*)(otb + ocell * 128 + ((ooff * 2) ^ ((ocell & 7) << 4))) = ro;
        if (t < 64) ts_s[t] = rts;
        __syncthreads();  // bar0: tiles + (first iter) weights ready

        if (b < 7) {
            const float* hsn = hiddens + ((size_t)((b + 1) * NCC + n0)) * HID;
            rh0 = *(const float4*)(hsn + flat);
            rh1 = *(const float4*)(hsn + flat + 4);
            ro  = *(const uint2*)(outu + (size_t)((b + 1) * NCC + n0 + ocell) * 256 + 192 + ooff);
            if (t < 64) rts = ws[WS_TS + (size_t)(b + 1) * NCC + n0 + t];
        }

        // ---- GRU: gi (K=64 from otb x WIH@L2) + gh (K=128 from hsb x WHH@LDS) ----
        {
            float* nbase = newh + ((size_t)(b * NCC + n0)) * HID;
            const int ra = r0 + col;
#pragma unroll
            for (int hgi = 0; hgi < 2; hgi++) {
                const int hg = hq * 2 + hgi;
                const int h = hg * 16 + col;
                f32x4 R = {0.f,0.f,0.f,0.f};
                f32x4 Z = {0.f,0.f,0.f,0.f};
                f32x4 I = {0.f,0.f,0.f,0.f};
                f32x4 N = {0.f,0.f,0.f,0.f};
#pragma unroll
                for (int ks = 0; ks < 2; ks++) {
                    short8 a0 = *(const short8*)(otb + ra * 128 +
                                 ((ks * 64 + (kq << 4)) ^ ((ra & 7) << 4)));
                    R = MFMA(a0, WIHF[(hg * 2 + ks) * 64 + lane], R);
                    Z = MFMA(a0, WIHF[((hg + 8) * 2 + ks) * 64 + lane], Z);
                    I = MFMA(a0, WIHF[((hg + 16) * 2 + ks) * 64 + lane], I);
                }
#pragma unroll
                for (int ks = 0; ks < 4; ks++) {
                    short8 a0 = *(const short8*)(hsb + ra * 256 +
                                 ((ks * 64 + (kq << 4)) ^ ((ra & 7) << 4)));
                    R = MFMA(a0, WHHF[(hg * 4 + ks) * 64 + lane], R);
                    Z = MFMA(a0, WHHF[((hg + 8) * 4 + ks) * 64 + lane], Z);
                    N = MFMA(a0, WHHF[((hg + 16) * 4 + ks) * 64 + lane], N);
                }
                const float bsr = ws[WS_BSUMR + h];
                const float bsz = ws[WS_BSUMZ + h];
                const float bin = ws[WS_BIHN + h];
                const float bhn = ws[WS_BHHN + h];
                const float wr  = ws[WS_W64 + h];
                const float wz  = ws[WS_W64 + 128 + h];
                const float wn  = ws[WS_W64 + 256 + h];
                float flsum = 0.f;
#pragma unroll
                for (int j = 0; j < 4; j++) {
                    int row = r0 + (kq << 2) + j;
                    float tv = ts_s[row] * (1.f / 64.f);
                    float r  = sigm(R[j] + bsr + tv * wr);
                    float z  = sigm(Z[j] + bsz + tv * wz);
                    float hn = N[j] + bhn;
                    float nn = tanh_fast(I[j] + bin + tv * wn + r * hn);
                    float hold = b2f(*(const unsigned short*)(hsb + row * 256 +
                                     ((h * 2) ^ ((row & 7) << 4))));
                    float nh = (1.f - z) * nn + z * hold;
                    nbase[(size_t)row * HID + h] = nh;
                    flsum += nh;
                }
                flsum += __shfl_xor(flsum, 16);
                flsum += __shfl_xor(flsum, 32);
                if (kq == 0) fp4[rg][h] = flsum;   // unique writer per (rg,h)
            }
        }
        __syncthreads();  // barC: tile reads + fp4 done

        if (t < 128)
            ws[WS_FPART + ((size_t)(b * 256 + chunk)) * 128 + t] =
                fp4[0][t] + fp4[1][t] + fp4[2][t] + fp4[3][t];
    }
}

// ---------------- faction means + debate-slice sums (256 chunks of 64) -----
__global__ __launch_bounds__(128) void k2_fmean(float* __restrict__ ws)
{
    int bf = blockIdx.x;
    int b = bf >> 3, f = bf & 7;
    int h = threadIdx.x;
    float s = 0.f, s8 = 0.f;
    for (int j = 0; j < 32; j++) {     // 32 chunks of 64 cells per faction
        float v = ws[WS_FPART + ((size_t)(b * 256 + f * 32 + j)) * 128 + h];
        s += v;
        if (j < 8) s8 += v;            // first 512 cells = debate slice
    }
    ws[WS_FMEAN + (b * 8 + f) * 128 + h] = s * (1.f / 2048.f);
    ws[WS_SD + (b * 8 + f) * 128 + h] = s8;
}

// ---------------- interference matvec (glob/hm inline) ----------------
__global__ __launch_bounds__(256) void k4mv(
    const float* __restrict__ mixW, const float* __restrict__ mixb,
    const int* __restrict__ step, float* __restrict__ ws)
{
    __shared__ float hm[1024];
    __shared__ float red[256];
    int h0 = blockIdx.x, t = threadIdx.x;
    bool deb = (step[0] > 5);
    for (int j = t; j < 1024; j += 256) {
        int b = j >> 7, hh = j & 127;
        float s = 0.f, sd = 0.f;
        for (int f = 0; f < 8; f++) {
            s  += ws[WS_FMEAN + (b * 8 + f) * 128 + hh];
            sd += ws[WS_SD + (b * 8 + f) * 128 + hh];
        }
        float gl = s * 0.125f;
        float tot = 16384.f * gl;
        if (deb) tot += 0.15f * (3481.6f * gl - 0.85f * sd);
        hm[j] = tot * (1.f / 16384.f);
    }
    __syncthreads();
    float4 wv = *(const float4*)(mixW + (size_t)h0 * 1024 + t * 4);
    float4 hv = *(const float4*)(&hm[t * 4]);
    float s = wv.x * hv.x + wv.y * hv.y + wv.z * hv.z + wv.w * hv.w;
    red[t] = s; __syncthreads();
    for (int st = 128; st > 0; st >>= 1) { if (t < st) red[t] += red[t + st]; __syncthreads(); }
    if (t == 0) ws[WS_INTERF + h0] = mixb[h0] + red[0];
}

// ---------------- fused sync/debate blend + interf apply (float4) ---------
__global__ __launch_bounds__(256) void k35_blend(
    float* __restrict__ newh, const float* __restrict__ ws,
    const int* __restrict__ step)
{
    int blk = blockIdx.x;              // 2048 = 8 * 256
    int b = blk >> 8, ck = blk & 255;
    int t = threadIdx.x;
    int h4 = t & 31;
    int cg = t >> 5;
    int base = ck * 64;
    int f = base >> 11;
    bool deb = (step[0] > 5) && ((base & 2047) < 512);
    float4 fm = *(const float4*)(ws + WS_FMEAN + (size_t)(b * 8 + f) * 128 + h4 * 4);
    float glx = 0.f, gly = 0.f, glz = 0.f, glw = 0.f;
    for (int ff = 0; ff < 8; ff++) {
        float4 v = *(const float4*)(ws + WS_FMEAN + (size_t)(b * 8 + ff) * 128 + h4 * 4);
        glx += v.x; gly += v.y; glz += v.z; glw += v.w;
    }
    glx *= 0.125f; gly *= 0.125f; glz *= 0.125f; glw *= 0.125f;
    float4 itf = {0.f, 0.f, 0.f, 0.f};
    if (b == 0) {
        float4 iv = *(const float4*)(ws + WS_INTERF + h4 * 4);
        itf.x = 0.05f * iv.x; itf.y = 0.05f * iv.y;
        itf.z = 0.05f * iv.z; itf.w = 0.05f * iv.w;
    }
    for (int i = 0; i < 8; i++) {
        int cell = base + i * 8 + cg;
        size_t idx = ((size_t)b * NCC + cell) * 128 + h4 * 4;
        float4 v = *(float4*)(newh + idx);
        v.x = 0.85f * v.x + 0.15f * fm.x;
        v.y = 0.85f * v.y + 0.15f * fm.y;
        v.z = 0.85f * v.z + 0.15f * fm.z;
        v.w = 0.85f * v.w + 0.15f * fm.w;
        if (deb) {
            v.x = 0.85f * v.x + 0.15f * glx;
            v.y = 0.85f * v.y + 0.15f * gly;
            v.z = 0.85f * v.z + 0.15f * glz;
            v.w = 0.85f * v.w + 0.15f * glw;
        }
        v.x += itf.x; v.y += itf.y; v.z += itf.z; v.w += itf.w;
        *(float4*)(newh + idx) = v;
    }
}

// ---------------- softmax-weighted cell_out partials (no-max exp) ---------
__global__ __launch_bounds__(256) void kred(float* __restrict__ ws)
{
    __shared__ float wexp[64];
    __shared__ float red[256];
    int blk = blockIdx.x, t = threadIdx.x;
    int n0 = blk * 64;
    float av = 0.f;
    if (t < 64) {
        av = ws[WS_AVGT + n0 + t];
        wexp[t] = __expf(av);
    }
    __syncthreads();
    int d = t & 63, q = t >> 6;
    float s = 0.f;
    for (int i = 0; i < 16; i++) {
        int c = q * 16 + i;
        s += wexp[c] * ws[WS_CO + (size_t)(n0 + c) * 64 + d];
    }
    red[t] = s; __syncthreads();
    if (t < 64)
        ws[WS_PART2 + blk * 64 + t] = red[t] + red[64 + t] + red[128 + t] + red[192 + t];
    if (t < 64) {
        float e = wexp[t], a2 = av;
        e  += __shfl_xor(e, 1);  a2 += __shfl_xor(a2, 1);
        e  += __shfl_xor(e, 2);  a2 += __shfl_xor(a2, 2);
        e  += __shfl_xor(e, 4);  a2 += __shfl_xor(a2, 4);
        e  += __shfl_xor(e, 8);  a2 += __shfl_xor(a2, 8);
        e  += __shfl_xor(e, 16); a2 += __shfl_xor(a2, 16);
        e  += __shfl_xor(e, 32); a2 += __shfl_xor(a2, 32);
        if (t == 0) { ws[WS_PARTE + blk] = e; ws[WS_PARTA + blk] = a2; }
    }
}

__global__ __launch_bounds__(256) void kpred(
    const float* __restrict__ headW, const float* __restrict__ headb,
    float* __restrict__ ws, float* __restrict__ d_out)
{
    __shared__ float red[256];
    __shared__ float num[64];
    __shared__ float den_s;
    int t = threadIdx.x;
    int d = t & 63, q = t >> 6;
    float s = 0.f;
    for (int i = 0; i < 64; i++) s += ws[WS_PART2 + (q * 64 + i) * 64 + d];
    red[t] = s; __syncthreads();
    if (t < 64) num[t] = red[t] + red[64 + t] + red[128 + t] + red[192 + t];
    __syncthreads();
    red[t] = ws[WS_PARTE + t]; __syncthreads();
    for (int st = 128; st > 0; st >>= 1) { if (t < st) red[t] += red[t + st]; __syncthreads(); }
    if (t == 0) den_s = red[0];
    __syncthreads();
    red[t] = ws[WS_PARTA + t]; __syncthreads();
    for (int st = 128; st > 0; st >>= 1) { if (t < st) red[t] += red[t + st]; __syncthreads(); }
    if (t == 0) d_out[64] = red[0] * (1.f / (float)NCC);
    __syncthreads();
    if (t < 64) {
        float inv_den = 1.f / den_s;
        float p = headb[t];
        for (int d2 = 0; d2 < 64; d2++) p += (num[d2] * inv_den) * headW[t * 64 + d2];
        d_out[t] = p;
    }
}

extern "C" void kernel_launch(void* const* d_in, const int* in_sizes, int n_in,
                              void* d_out, int out_size, void* d_ws, size_t ws_size,
                              hipStream_t stream)
{
    const float* x       = (const float*)d_in[0];
    const float* noise   = (const float*)d_in[1];
    const float* amps    = (const float*)d_in[2];
    const float* hiddens = (const float*)d_in[3];
    const float* eaW1    = (const float*)d_in[4];
    const float* eaB1    = (const float*)d_in[5];
    const float* eaW2    = (const float*)d_in[6];
    const float* eaB2    = (const float*)d_in[7];
    const float* egW1    = (const float*)d_in[8];
    const float* egB1    = (const float*)d_in[9];
    const float* egW2    = (const float*)d_in[10];
    const float* egB2    = (const float*)d_in[11];
    const float* gWih    = (const float*)d_in[12];
    const float* gWhh    = (const float*)d_in[13];
    const float* gbih    = (const float*)d_in[14];
    const float* gbhh    = (const float*)d_in[15];
    const float* headW   = (const float*)d_in[16];
    const float* headb   = (const float*)d_in[17];
    const float* mixW    = (const float*)d_in[18];
    const float* mixb    = (const float*)d_in[19];
    const int*   step    = (const int*)d_in[20];

    float* out  = (float*)d_out;
    float* newh = out + 65;   // [pred(64), avg_t_mean(1), newh(8*16384*128)]
    float* ws   = (float*)d_ws;

    kprep<<<120, 1024, 0, stream>>>(x, noise, amps, eaW1, eaB1, egW1, egB1,
                                    eaW2, eaB2, egW2, egB2, gWih, gWhh,
                                    gbih, gbhh, ws);
    kA<<<256, 1024, 0, stream>>>(hiddens, newh, ws);
    kB<<<256, 1024, 0, stream>>>(hiddens, newh, ws);
    k2_fmean<<<64, 128, 0, stream>>>(ws);
    k4mv<<<128, 256, 0, stream>>>(mixW, mixb, step, ws);
    k35_blend<<<2048, 256, 0, stream>>>(newh, ws, step);
    kred<<<256, 256, 0, stream>>>(ws);
    kpred<<<1, 256, 0, stream>>>(headW, headb, ws, out);
}

// Round 14
// 124.616 us; speedup vs baseline: 1.2461x; 1.2461x over previous
//
#include <hip/hip_runtime.h>
#include <math.h>

#define NB   8
#define NCC  16384
#define HID  128

typedef __attribute__((ext_vector_type(8))) short short8;
typedef __attribute__((ext_vector_type(4))) float f32x4;

#define MFMA(a,b,c) __builtin_amdgcn_mfma_f32_16x16x32_bf16(a,b,c,0,0,0)

// ---- ws float offsets ----
#define WS_AABS   0
#define WS_BASE1  8
#define WS_BOUT   2056
#define WS_BSUMR  2120
#define WS_BSUMZ  2248
#define WS_BIHN   2376
#define WS_BHHN   2504
#define WS_W64    2632
#define WS_INTERF 3024
#define WS_FRAG   3152      // 61440 floats = 122880 bf16 frags (W1|W2|WIH|WHH)
#define WS_SD     64592     // 64*128
#define WS_AVGT   73808     // 16384 (plain store per chunk by kA)
#define WS_TS     90192     // 8*16384 raw sum(out^2) per (b,cell)
#define WS_FMEAN  221264    // 64*128
#define WS_PART2  230480    // 256*64
#define WS_FPART  246864    // 8*512*128 (unique writer per (b,chunk32))
#define WS_CO     771152    // 16384*64 f32 (unique writer per chunk64)
#define WS_PARTE  1819728   // 256 exp-sum partials
#define WS_PARTA  1819984   // 256 avgt-sum partials

__device__ __forceinline__ unsigned short f2b(float f) {
    unsigned int u = __float_as_uint(f);
    unsigned int r = (u + 0x7fffu + ((u >> 16) & 1u)) >> 16;
    return (unsigned short)r;
}
__device__ __forceinline__ float b2f(unsigned short us) {
    return __uint_as_float(((unsigned int)us) << 16);
}
__device__ __forceinline__ float sigm(float x) {
    return __builtin_amdgcn_rcpf(1.f + __expf(-x));
}
__device__ __forceinline__ float tanh_fast(float x) {
    return 1.f - 2.f * __builtin_amdgcn_rcpf(__expf(2.f * x) + 1.f);
}
__device__ __forceinline__ unsigned int cvtpk(float lo, float hi) {
    unsigned int r;
    asm volatile("v_cvt_pk_bf16_f32 %0, %1, %2" : "=v"(r) : "v"(lo), "v"(hi));
    return r;
}
__device__ __forceinline__ void stg(char* dst, int row, int cb, float4 u, float4 v) {
    uint4 pk = make_uint4(cvtpk(u.x, u.y), cvtpk(u.z, u.w),
                          cvtpk(v.x, v.y), cvtpk(v.z, v.w));
    *(uint4*)(dst + row * 256 + (cb ^ ((row & 7) << 4))) = pk;
}

// ---------------- prep: fragment pre-swizzle + (block 0) scalars ----------------
__global__ __launch_bounds__(1024) void kprep(
    const float* __restrict__ x, const float* __restrict__ noise,
    const float* __restrict__ amps,
    const float* __restrict__ eaW1, const float* __restrict__ eaB1,
    const float* __restrict__ egW1, const float* __restrict__ egB1,
    const float* __restrict__ eaW2, const float* __restrict__ eaB2,
    const float* __restrict__ egW2, const float* __restrict__ egB2,
    const float* __restrict__ gWih, const float* __restrict__ gWhh,
    const float* __restrict__ gbih, const float* __restrict__ gbhh,
    float* __restrict__ ws)
{
    int i = blockIdx.x * 1024 + threadIdx.x;
    if (i < 122880) {
        short* wsh = (short*)(ws + WS_FRAG);
        float v;
        if (i < 32768) {                       // W1: K=128, N=256 (a|g), KT=4
            int rel = i;
            int j = rel & 7, l = (rel >> 3) & 63, tk = rel >> 9;
            int kt = tk & 3, nt = tk >> 2;
            int n = nt * 16 + (l & 15), k = kt * 32 + ((l >> 4) << 3) + j;
            v = (n < 128) ? eaW1[n * 192 + 64 + k] : egW1[(n - 128) * 192 + 64 + k];
        } else if (i < 49152) {                // W2: K=256 ([A1|G1]), N=64, KT=8
            int rel = i - 32768;
            int j = rel & 7, l = (rel >> 3) & 63, tk = rel >> 9;
            int kt = tk & 7, nt = tk >> 3;
            int d = nt * 16 + (l & 15), k = kt * 32 + ((l >> 4) << 3) + j;
            v = (k < 128) ? eaW2[d * 128 + k] : -egW2[d * 128 + (k - 128)];
        } else if (i < 73728) {                // WIH: K=64, N=384, KT=2
            int rel = i - 49152;
            int j = rel & 7, l = (rel >> 3) & 63, tk = rel >> 9;
            int kt = tk & 1, nt = tk >> 1;
            int r = nt * 16 + (l & 15), k = kt * 32 + ((l >> 4) << 3) + j;
            v = gWih[r * 65 + k];
        } else {                               // WHH: K=128, N=384, KT=4
            int rel = i - 73728;
            int j = rel & 7, l = (rel >> 3) & 63, tk = rel >> 9;
            int kt = tk & 3, nt = tk >> 2;
            int r = nt * 16 + (l & 15), k = kt * 32 + ((l >> 4) << 3) + j;
            v = gWhh[r * 128 + k];
        }
        wsh[i] = (short)f2b(v);
    }
    if (blockIdx.x == 0) {
        __shared__ float xb[8][64];
        int t = threadIdx.x;
        if (t < 512) {
            int b = t >> 6, k = t & 63;
            xb[b][k] = x[k] + noise[b * 64 + k] * (0.05f * (float)(b + 1));
        }
        if (t == 0) {
            float s = 0.f;
            for (int b = 0; b < 8; b++) s += fabsf(amps[b]);
            s += 1e-8f;
            for (int b = 0; b < 8; b++) ws[WS_AABS + b] = fabsf(amps[b]) / s;
        }
        __syncthreads();
        for (int ii = t; ii < 2048; ii += 1024) {
            int b = ii >> 8, n = ii & 255;
            const float* Wp; float s;
            if (n < 128) { Wp = eaW1 + n * 192; s = eaB1[n]; }
            else         { Wp = egW1 + (n - 128) * 192; s = egB1[n - 128]; }
            for (int k = 0; k < 64; k++) s += xb[b & 7][k] * Wp[k];
            ws[WS_BASE1 + ii] = s;
        }
        if (t < 64) ws[WS_BOUT + t] = eaB2[t] - egB2[t];
        if (t < 128) {
            ws[WS_BSUMR + t] = gbih[t] + gbhh[t];
            ws[WS_BSUMZ + t] = gbih[128 + t] + gbhh[128 + t];
            ws[WS_BIHN + t]  = gbih[256 + t];
            ws[WS_BHHN + t]  = gbhh[256 + t];
        }
        if (t < 384) ws[WS_W64 + t] = gWih[t * 65 + 64];
    }
}

// ================= kA: L1 + L2, weights LDS-resident, 16 waves =================
__global__ __launch_bounds__(1024) void kA(
    const float* __restrict__ hiddens, float* __restrict__ newh,
    float* __restrict__ ws)
{
    __shared__ char  wlds[98304];       // W1L @0 (64KB), W2L @65536 (32KB)
    __shared__ char  hsb[64 * 256];     // bf16 [64][128] swizzled (16KB)
    __shared__ char  agb[64 * 512];     // bf16 [64][256] (32KB)
    __shared__ float ts_s[64];
    __shared__ float tsum_s[64];

    const int t    = threadIdx.x;
    const int lane = t & 63;
    const int w    = t >> 6;
    const int rg   = w >> 2;
    const int nq   = w & 3;
    const int col  = lane & 15;
    const int kq   = lane >> 4;
    const int r0   = rg * 16;
    const int n0   = blockIdx.x * 64;

    {
        const float4* src = (const float4*)(ws + WS_FRAG);
        float4* dst = (float4*)wlds;
#pragma unroll
        for (int p = 0; p < 6; p++) dst[p * 1024 + t] = src[p * 1024 + t];
    }
    const short8* W1F = (const short8*)wlds;
    const short8* W2F = (const short8*)(wlds + 65536);

    const float bo = ws[WS_BOUT + nq * 16 + col];
    float co_reg[4];
#pragma unroll
    for (int i = 0; i < 4; i++) co_reg[i] = 0.f;
    if (t < 64) tsum_s[t] = 0.f;

    const int flat = t * 8;
    const int srow = flat >> 7;
    const int scb  = (flat & 127) * 2;

    {
        const float* hs = hiddens + (size_t)n0 * HID;
        float4 a0 = *(const float4*)(hs + flat);
        float4 a1 = *(const float4*)(hs + flat + 4);
        stg(hsb, srow, scb, a0, a1);
    }
    float4 pfa0, pfa1;
    unsigned short* outu = (unsigned short*)newh;

    for (int b = 0; b < NB; ++b) {
        __syncthreads();  // bar0
        if (t < 64) {
            if (b > 0) {
                ws[WS_TS + (size_t)(b - 1) * NCC + n0 + t] = ts_s[t];
                tsum_s[t] += ts_s[t];
            }
            ts_s[t] = 0.f;
        }
        if (b < 7) {
            const float* hsn = hiddens + ((size_t)((b + 1) * NCC + n0)) * HID;
            pfa0 = *(const float4*)(hsn + flat);
            pfa1 = *(const float4*)(hsn + flat + 4);
        }

        // ---- L1 ----
        {
            short8 aH[4];
#pragma unroll
            for (int ks = 0; ks < 4; ks++) {
                int row = r0 + col;
                aH[ks] = *(const short8*)(hsb + row * 256 +
                           ((ks * 64 + (kq << 4)) ^ ((row & 7) << 4)));
            }
#pragma unroll
            for (int nti = 0; nti < 4; nti++) {
                int nt = nq * 4 + nti;
                f32x4 ac = {0.f, 0.f, 0.f, 0.f};
#pragma unroll
                for (int kt = 0; kt < 4; kt++)
                    ac = MFMA(aH[kt], W1F[(nt * 4 + kt) * 64 + lane], ac);
                int n = nt * 16 + col;
                float bs = ws[WS_BASE1 + b * 256 + n];
#pragma unroll
                for (int j = 0; j < 4; j++) {
                    int row = r0 + (kq << 2) + j;
                    float v = fmaxf(ac[j] + bs, 0.f);
                    *(unsigned short*)(agb + row * 512 +
                        ((n * 2) ^ ((row & 7) << 4))) = f2b(v);
                }
            }
        }
        __syncthreads();  // barA

        if (b < 7) stg(hsb, srow, scb, pfa0, pfa1);

        // ---- L2 ----
        {
            f32x4 ov = {0.f, 0.f, 0.f, 0.f};
#pragma unroll
            for (int kt = 0; kt < 8; kt++) {
                int kb = kt * 64 + (kq << 4);
                int ra = r0 + col;
                short8 a0 = *(const short8*)(agb + ra * 512 + (kb ^ ((ra & 7) << 4)));
                ov = MFMA(a0, W2F[(nq * 8 + kt) * 64 + lane], ov);
            }
            int d = nq * 16 + col;
            float aab = ws[WS_AABS + b];
#pragma unroll
            for (int j = 0; j < 4; j++) {
                int row = r0 + (kq << 2) + j;
                float v = ov[j] + bo;
                co_reg[j] += aab * v;
                outu[(size_t)(b * NCC + n0 + row) * 256 + 192 + d] = f2b(v);
                float sq = v * v;
                sq += __shfl_xor(sq, 1);
                sq += __shfl_xor(sq, 2);
                sq += __shfl_xor(sq, 4);
                sq += __shfl_xor(sq, 8);
                if (col == 0) atomicAdd(&ts_s[row], sq);
            }
        }
    }
    __syncthreads();
    if (t < 64) {
        ws[WS_TS + (size_t)7 * NCC + n0 + t] = ts_s[t];
        tsum_s[t] += ts_s[t];
        ws[WS_AVGT + n0 + t] = tsum_s[t] * (1.f / 512.f);
    }
    {
        int d = nq * 16 + col;
#pragma unroll
        for (int j = 0; j < 4; j++) {
            int row = r0 + (kq << 2) + j;
            ws[WS_CO + (size_t)(n0 + row) * 64 + d] = co_reg[j];
        }
    }
}

// ================= kB: GRU, weights LDS-resident, 16 waves =================
__global__ __launch_bounds__(1024) void kB(
    const float* __restrict__ hiddens, float* __restrict__ newh,
    float* __restrict__ ws)
{
    __shared__ char  wl[147456];        // WIH @0 (48KB), WHH @49152 (96KB)
    __shared__ char  hsb[32 * 256];
    __shared__ char  otb[32 * 128];
    __shared__ float ts_s[32];
    __shared__ float fp2[2][128];

    const int t    = threadIdx.x;
    const int lane = t & 63;
    const int w    = t >> 6;
    const int rh   = w >> 3;
    const int hg   = w & 7;
    const int col  = lane & 15;
    const int kq   = lane >> 4;
    const int chunk = blockIdx.x;
    const int n0   = chunk * 32;

    {
        const float4* src = (const float4*)(ws + WS_FRAG) + 6144;
        float4* dst = (float4*)wl;
#pragma unroll
        for (int p = 0; p < 9; p++) dst[p * 1024 + t] = src[p * 1024 + t];
    }
    const short8* WIHF = (const short8*)wl;
    const short8* WHHF = (const short8*)(wl + 49152);
    const unsigned short* outu = (const unsigned short*)newh;

    const int h = hg * 16 + col;
    const float bsr = ws[WS_BSUMR + h];
    const float bsz = ws[WS_BSUMZ + h];
    const float bin = ws[WS_BIHN + h];
    const float bhn = ws[WS_BHHN + h];
    const float wr  = ws[WS_W64 + h];
    const float wz  = ws[WS_W64 + 128 + h];
    const float wn  = ws[WS_W64 + 256 + h];

    const int flat = t * 8;
    const int srow = flat >> 7;
    const int scb  = (flat & 127) * 2;
    const int ocell = t >> 4;
    const int ooff  = (t & 15) * 4;

    float4 rh0 = {0,0,0,0}, rh1 = {0,0,0,0};
    uint2  ro = make_uint2(0, 0);
    float  rts = 0.f;
    if (t < 512) {
        const float* hs = hiddens + (size_t)n0 * HID;
        rh0 = *(const float4*)(hs + flat);
        rh1 = *(const float4*)(hs + flat + 4);
        ro  = *(const uint2*)(outu + (size_t)(n0 + ocell) * 256 + 192 + ooff);
    }
    if (t < 32) rts = ws[WS_TS + n0 + t];

    for (int b = 0; b < NB; ++b) {
        if (t < 512) {
            stg(hsb, srow, scb, rh0, rh1);
            *(uint2*)(otb + ocell * 128 + ((ooff * 2) ^ ((ocell & 7) << 4))) = ro;
        }
        if (t < 32) ts_s[t] = rts;
        __syncthreads();  // bar0

        if (b < 7) {
            if (t < 512) {
                const float* hsn = hiddens + ((size_t)((b + 1) * NCC + n0)) * HID;
                rh0 = *(const float4*)(hsn + flat);
                rh1 = *(const float4*)(hsn + flat + 4);
                ro  = *(const uint2*)(outu + (size_t)((b + 1) * NCC + n0 + ocell) * 256 + 192 + ooff);
            }
            if (t < 32) rts = ws[WS_TS + (size_t)(b + 1) * NCC + n0 + t];
        }

        // ---- GRU ----
        {
            float* nbase = newh + ((size_t)(b * NCC + n0)) * HID;
            const int ra = rh * 16 + col;
            f32x4 R = {0.f,0.f,0.f,0.f};
            f32x4 Z = {0.f,0.f,0.f,0.f};
            f32x4 I = {0.f,0.f,0.f,0.f};
            f32x4 N = {0.f,0.f,0.f,0.f};
#pragma unroll
            for (int ks = 0; ks < 2; ks++) {
                short8 a0 = *(const short8*)(otb + ra * 128 +
                             ((ks * 64 + (kq << 4)) ^ ((ra & 7) << 4)));
                R = MFMA(a0, WIHF[(hg * 2 + ks) * 64 + lane], R);
                Z = MFMA(a0, WIHF[((hg + 8) * 2 + ks) * 64 + lane], Z);
                I = MFMA(a0, WIHF[((hg + 16) * 2 + ks) * 64 + lane], I);
            }
#pragma unroll
            for (int ks = 0; ks < 4; ks++) {
                short8 a0 = *(const short8*)(hsb + ra * 256 +
                             ((ks * 64 + (kq << 4)) ^ ((ra & 7) << 4)));
                R = MFMA(a0, WHHF[(hg * 4 + ks) * 64 + lane], R);
                Z = MFMA(a0, WHHF[((hg + 8) * 4 + ks) * 64 + lane], Z);
                N = MFMA(a0, WHHF[((hg + 16) * 4 + ks) * 64 + lane], N);
            }
            float flsum = 0.f;
#pragma unroll
            for (int j = 0; j < 4; j++) {
                int row = rh * 16 + (kq << 2) + j;
                float tv = ts_s[row] * (1.f / 64.f);
                float r  = sigm(R[j] + bsr + tv * wr);
                float z  = sigm(Z[j] + bsz + tv * wz);
                float hn = N[j] + bhn;
                float nn = tanh_fast(I[j] + bin + tv * wn + r * hn);
                float hold = b2f(*(const unsigned short*)(hsb + row * 256 +
                                 ((h * 2) ^ ((row & 7) << 4))));
                float nh = (1.f - z) * nn + z * hold;
                nbase[(size_t)row * HID + h] = nh;
                flsum += nh;
            }
            flsum += __shfl_xor(flsum, 16);
            flsum += __shfl_xor(flsum, 32);
            if (kq == 0) fp2[rh][h] = flsum;
        }
        __syncthreads();  // barC

        if (t < 128)
            ws[WS_FPART + ((size_t)(b * 512 + chunk)) * 128 + t] = fp2[0][t] + fp2[1][t];
    }
}

// ---------------- merged: kred (blocks 0-255) + fmean (blocks 256-319) -----
__global__ __launch_bounds__(256) void kfr(float* __restrict__ ws)
{
    int blk = blockIdx.x, t = threadIdx.x;
    if (blk < 256) {
        // kred: softmax-weighted cell_out partials (no-max exp)
        __shared__ float wexp[64];
        __shared__ float red[256];
        int n0 = blk * 64;
        float av = 0.f;
        if (t < 64) {
            av = ws[WS_AVGT + n0 + t];
            wexp[t] = __expf(av);
        }
        __syncthreads();
        int d = t & 63, q = t >> 6;
        float s = 0.f;
        for (int i = 0; i < 16; i++) {
            int c = q * 16 + i;
            s += wexp[c] * ws[WS_CO + (size_t)(n0 + c) * 64 + d];
        }
        red[t] = s; __syncthreads();
        if (t < 64)
            ws[WS_PART2 + blk * 64 + t] = red[t] + red[64 + t] + red[128 + t] + red[192 + t];
        if (t < 64) {
            float e = wexp[t], a2 = av;
            e  += __shfl_xor(e, 1);  a2 += __shfl_xor(a2, 1);
            e  += __shfl_xor(e, 2);  a2 += __shfl_xor(a2, 2);
            e  += __shfl_xor(e, 4);  a2 += __shfl_xor(a2, 4);
            e  += __shfl_xor(e, 8);  a2 += __shfl_xor(a2, 8);
            e  += __shfl_xor(e, 16); a2 += __shfl_xor(a2, 16);
            e  += __shfl_xor(e, 32); a2 += __shfl_xor(a2, 32);
            if (t == 0) { ws[WS_PARTE + blk] = e; ws[WS_PARTA + blk] = a2; }
        }
    } else {
        // fmean: faction means + debate-slice sums
        int bf = blk - 256;
        int b = bf >> 3, f = bf & 7;
        if (t < 128) {
            int h = t;
            float s = 0.f, s8 = 0.f;
            for (int j = 0; j < 64; j++) {
                float v = ws[WS_FPART + ((size_t)(b * 512 + f * 64 + j)) * 128 + h];
                s += v;
                if (j < 16) s8 += v;
            }
            ws[WS_FMEAN + (b * 8 + f) * 128 + h] = s * (1.f / 2048.f);
            ws[WS_SD + (b * 8 + f) * 128 + h] = s8;
        }
    }
}

// ---------------- merged: k4mv (blocks 0-127) + kpred (block 128) ----------
__global__ __launch_bounds__(256) void kmp(
    const float* __restrict__ mixW, const float* __restrict__ mixb,
    const float* __restrict__ headW, const float* __restrict__ headb,
    const int* __restrict__ step, float* __restrict__ ws,
    float* __restrict__ d_out)
{
    int blk = blockIdx.x, t = threadIdx.x;
    if (blk < 128) {
        // interference matvec (glob/hm inline)
        __shared__ float hm[1024];
        __shared__ float red[256];
        bool deb = (step[0] > 5);
        for (int j = t; j < 1024; j += 256) {
            int b = j >> 7, hh = j & 127;
            float s = 0.f, sd = 0.f;
            for (int f = 0; f < 8; f++) {
                s  += ws[WS_FMEAN + (b * 8 + f) * 128 + hh];
                sd += ws[WS_SD + (b * 8 + f) * 128 + hh];
            }
            float gl = s * 0.125f;
            float tot = 16384.f * gl;
            if (deb) tot += 0.15f * (3481.6f * gl - 0.85f * sd);
            hm[j] = tot * (1.f / 16384.f);
        }
        __syncthreads();
        float4 wv = *(const float4*)(mixW + (size_t)blk * 1024 + t * 4);
        float4 hv = *(const float4*)(&hm[t * 4]);
        float s = wv.x * hv.x + wv.y * hv.y + wv.z * hv.z + wv.w * hv.w;
        red[t] = s; __syncthreads();
        for (int st = 128; st > 0; st >>= 1) { if (t < st) red[t] += red[t + st]; __syncthreads(); }
        if (t == 0) ws[WS_INTERF + blk] = mixb[blk] + red[0];
    } else {
        // kpred
        __shared__ float red[256];
        __shared__ float num[64];
        __shared__ float den_s;
        int d = t & 63, q = t >> 6;
        float s = 0.f;
        for (int i = 0; i < 64; i++) s += ws[WS_PART2 + (q * 64 + i) * 64 + d];
        red[t] = s; __syncthreads();
        if (t < 64) num[t] = red[t] + red[64 + t] + red[128 + t] + red[192 + t];
        __syncthreads();
        red[t] = ws[WS_PARTE + t]; __syncthreads();
        for (int st = 128; st > 0; st >>= 1) { if (t < st) red[t] += red[t + st]; __syncthreads(); }
        if (t == 0) den_s = red[0];
        __syncthreads();
        red[t] = ws[WS_PARTA + t]; __syncthreads();
        for (int st = 128; st > 0; st >>= 1) { if (t < st) red[t] += red[t + st]; __syncthreads(); }
        if (t == 0) d_out[64] = red[0] * (1.f / (float)NCC);
        __syncthreads();
        if (t < 64) {
            float inv_den = 1.f / den_s;
            float p = headb[t];
            for (int d2 = 0; d2 < 64; d2++) p += (num[d2] * inv_den) * headW[t * 64 + d2];
            d_out[t] = p;
        }
    }
}

// ---------------- fused sync/debate blend + interf apply (float4) ---------
__global__ __launch_bounds__(256) void k35_blend(
    float* __restrict__ newh, const float* __restrict__ ws,
    const int* __restrict__ step)
{
    int blk = blockIdx.x;              // 2048 = 8 * 256
    int b = blk >> 8, ck = blk & 255;
    int t = threadIdx.x;
    int h4 = t & 31;
    int cg = t >> 5;
    int base = ck * 64;
    int f = base >> 11;
    bool deb = (step[0] > 5) && ((base & 2047) < 512);
    float4 fm = *(const float4*)(ws + WS_FMEAN + (size_t)(b * 8 + f) * 128 + h4 * 4);
    float glx = 0.f, gly = 0.f, glz = 0.f, glw = 0.f;
    for (int ff = 0; ff < 8; ff++) {
        float4 v = *(const float4*)(ws + WS_FMEAN + (size_t)(b * 8 + ff) * 128 + h4 * 4);
        glx += v.x; gly += v.y; glz += v.z; glw += v.w;
    }
    glx *= 0.125f; gly *= 0.125f; glz *= 0.125f; glw *= 0.125f;
    float4 itf = {0.f, 0.f, 0.f, 0.f};
    if (b == 0) {
        float4 iv = *(const float4*)(ws + WS_INTERF + h4 * 4);
        itf.x = 0.05f * iv.x; itf.y = 0.05f * iv.y;
        itf.z = 0.05f * iv.z; itf.w = 0.05f * iv.w;
    }
    for (int i = 0; i < 8; i++) {
        int cell = base + i * 8 + cg;
        size_t idx = ((size_t)b * NCC + cell) * 128 + h4 * 4;
        float4 v = *(float4*)(newh + idx);
        v.x = 0.85f * v.x + 0.15f * fm.x;
        v.y = 0.85f * v.y + 0.15f * fm.y;
        v.z = 0.85f * v.z + 0.15f * fm.z;
        v.w = 0.85f * v.w + 0.15f * fm.w;
        if (deb) {
            v.x = 0.85f * v.x + 0.15f * glx;
            v.y = 0.85f * v.y + 0.15f * gly;
            v.z = 0.85f * v.z + 0.15f * glz;
            v.w = 0.85f * v.w + 0.15f * glw;
        }
        v.x += itf.x; v.y += itf.y; v.z += itf.z; v.w += itf.w;
        *(float4*)(newh + idx) = v;
    }
}

extern "C" void kernel_launch(void* const* d_in, const int* in_sizes, int n_in,
                              void* d_out, int out_size, void* d_ws, size_t ws_size,
                              hipStream_t stream)
{
    const float* x       = (const float*)d_in[0];
    const float* noise   = (const float*)d_in[1];
    const float* amps    = (const float*)d_in[2];
    const float* hiddens = (const float*)d_in[3];
    const float* eaW1    = (const float*)d_in[4];
    const float* eaB1    = (const float*)d_in[5];
    const float* eaW2    = (const float*)d_in[6];
    const float* eaB2    = (const float*)d_in[7];
    const float* egW1    = (const float*)d_in[8];
    const float* egB1    = (const float*)d_in[9];
    const float* egW2    = (const float*)d_in[10];
    const float* egB2    = (const float*)d_in[11];
    const float* gWih    = (const float*)d_in[12];
    const float* gWhh    = (const float*)d_in[13];
    const float* gbih    = (const float*)d_in[14];
    const float* gbhh    = (const float*)d_in[15];
    const float* headW   = (const float*)d_in[16];
    const float* headb   = (const float*)d_in[17];
    const float* mixW    = (const float*)d_in[18];
    const float* mixb    = (const float*)d_in[19];
    const int*   step    = (const int*)d_in[20];

    float* out  = (float*)d_out;
    float* newh = out + 65;   // [pred(64), avg_t_mean(1), newh(8*16384*128)]
    float* ws   = (float*)d_ws;

    kprep<<<120, 1024, 0, stream>>>(x, noise, amps, eaW1, eaB1, egW1, egB1,
                                    eaW2, eaB2, egW2, egB2, gWih, gWhh,
                                    gbih, gbhh, ws);
    kA<<<256, 1024, 0, stream>>>(hiddens, newh, ws);
    kB<<<512, 1024, 0, stream>>>(hiddens, newh, ws);
    kfr<<<320, 256, 0, stream>>>(ws);
    kmp<<<129, 256, 0, stream>>>(mixW, mixb, headW, headb, step, ws, out);
    k35_blend<<<2048, 256, 0, stream>>>(newh, ws, step);
}

// Round 15
// 119.258 us; speedup vs baseline: 1.3021x; 1.0449x over previous
//
#include <hip/hip_runtime.h>
#include <math.h>

#define NB   8
#define NCC  16384
#define HID  128

typedef __attribute__((ext_vector_type(8))) short short8;
typedef __attribute__((ext_vector_type(4))) float f32x4;

#define MFMA(a,b,c) __builtin_amdgcn_mfma_f32_16x16x32_bf16(a,b,c,0,0,0)

// ---- ws float offsets ----
#define WS_AABS   0
#define WS_BASE1  8
#define WS_BOUT   2056
#define WS_BSUMR  2120
#define WS_BSUMZ  2248
#define WS_BIHN   2376
#define WS_BHHN   2504
#define WS_W64    2632
#define WS_INTERF 3024
#define WS_FRAG   3152      // 61440 floats = 122880 bf16 frags (W1|W2|WIH|WHH)
#define WS_SD     64592     // 64*128
#define WS_AVGT   73808     // 16384
#define WS_TS     90192     // 8*16384
#define WS_FMEAN  221264    // 64*128
#define WS_PART2  230480    // 256*64
#define WS_FPART  246864    // 8*256*128 (unique writer per (b,chunk64))
#define WS_CO     771152    // 16384*64 f32
#define WS_PARTE  1819728   // 256
#define WS_PARTA  1819984   // 256

__device__ __forceinline__ unsigned short f2b(float f) {
    unsigned int u = __float_as_uint(f);
    unsigned int r = (u + 0x7fffu + ((u >> 16) & 1u)) >> 16;
    return (unsigned short)r;
}
__device__ __forceinline__ float b2f(unsigned short us) {
    return __uint_as_float(((unsigned int)us) << 16);
}
__device__ __forceinline__ float sigm(float x) {
    return __builtin_amdgcn_rcpf(1.f + __expf(-x));
}
__device__ __forceinline__ float tanh_fast(float x) {
    return 1.f - 2.f * __builtin_amdgcn_rcpf(__expf(2.f * x) + 1.f);
}
__device__ __forceinline__ unsigned int cvtpk(float lo, float hi) {
    unsigned int r;
    asm volatile("v_cvt_pk_bf16_f32 %0, %1, %2" : "=v"(r) : "v"(lo), "v"(hi));
    return r;
}
__device__ __forceinline__ void stg(char* dst, int row, int cb, float4 u, float4 v) {
    uint4 pk = make_uint4(cvtpk(u.x, u.y), cvtpk(u.z, u.w),
                          cvtpk(v.x, v.y), cvtpk(v.z, v.w));
    *(uint4*)(dst + row * 256 + (cb ^ ((row & 7) << 4))) = pk;
}

// ---------------- prep: fragment pre-swizzle + (block 0) scalars ----------------
__global__ __launch_bounds__(1024) void kprep(
    const float* __restrict__ x, const float* __restrict__ noise,
    const float* __restrict__ amps,
    const float* __restrict__ eaW1, const float* __restrict__ eaB1,
    const float* __restrict__ egW1, const float* __restrict__ egB1,
    const float* __restrict__ eaW2, const float* __restrict__ eaB2,
    const float* __restrict__ egW2, const float* __restrict__ egB2,
    const float* __restrict__ gWih, const float* __restrict__ gWhh,
    const float* __restrict__ gbih, const float* __restrict__ gbhh,
    float* __restrict__ ws)
{
    int i = blockIdx.x * 1024 + threadIdx.x;
    if (i < 122880) {
        short* wsh = (short*)(ws + WS_FRAG);
        float v;
        if (i < 32768) {                       // W1: K=128, N=256 (a|g), KT=4
            int rel = i;
            int j = rel & 7, l = (rel >> 3) & 63, tk = rel >> 9;
            int kt = tk & 3, nt = tk >> 2;
            int n = nt * 16 + (l & 15), k = kt * 32 + ((l >> 4) << 3) + j;
            v = (n < 128) ? eaW1[n * 192 + 64 + k] : egW1[(n - 128) * 192 + 64 + k];
        } else if (i < 49152) {                // W2: K=256 ([A1|G1]), N=64, KT=8
            int rel = i - 32768;
            int j = rel & 7, l = (rel >> 3) & 63, tk = rel >> 9;
            int kt = tk & 7, nt = tk >> 3;
            int d = nt * 16 + (l & 15), k = kt * 32 + ((l >> 4) << 3) + j;
            v = (k < 128) ? eaW2[d * 128 + k] : -egW2[d * 128 + (k - 128)];
        } else if (i < 73728) {                // WIH: K=64, N=384, KT=2
            int rel = i - 49152;
            int j = rel & 7, l = (rel >> 3) & 63, tk = rel >> 9;
            int kt = tk & 1, nt = tk >> 1;
            int r = nt * 16 + (l & 15), k = kt * 32 + ((l >> 4) << 3) + j;
            v = gWih[r * 65 + k];
        } else {                               // WHH: K=128, N=384, KT=4
            int rel = i - 73728;
            int j = rel & 7, l = (rel >> 3) & 63, tk = rel >> 9;
            int kt = tk & 3, nt = tk >> 2;
            int r = nt * 16 + (l & 15), k = kt * 32 + ((l >> 4) << 3) + j;
            v = gWhh[r * 128 + k];
        }
        wsh[i] = (short)f2b(v);
    }
    if (blockIdx.x == 0) {
        __shared__ float xb[8][64];
        int t = threadIdx.x;
        if (t < 512) {
            int b = t >> 6, k = t & 63;
            xb[b][k] = x[k] + noise[b * 64 + k] * (0.05f * (float)(b + 1));
        }
        if (t == 0) {
            float s = 0.f;
            for (int b = 0; b < 8; b++) s += fabsf(amps[b]);
            s += 1e-8f;
            for (int b = 0; b < 8; b++) ws[WS_AABS + b] = fabsf(amps[b]) / s;
        }
        __syncthreads();
        for (int ii = t; ii < 2048; ii += 1024) {
            int b = ii >> 8, n = ii & 255;
            const float* Wp; float s;
            if (n < 128) { Wp = eaW1 + n * 192; s = eaB1[n]; }
            else         { Wp = egW1 + (n - 128) * 192; s = egB1[n - 128]; }
            for (int k = 0; k < 64; k++) s += xb[b & 7][k] * Wp[k];
            ws[WS_BASE1 + ii] = s;
        }
        if (t < 64) ws[WS_BOUT + t] = eaB2[t] - egB2[t];
        if (t < 128) {
            ws[WS_BSUMR + t] = gbih[t] + gbhh[t];
            ws[WS_BSUMZ + t] = gbih[128 + t] + gbhh[128 + t];
            ws[WS_BIHN + t]  = gbih[256 + t];
            ws[WS_BHHN + t]  = gbhh[256 + t];
        }
        if (t < 384) ws[WS_W64 + t] = gWih[t * 65 + 64];
    }
}

// ================= kA: L1 + L2, weights LDS-resident, 16 waves =================
__global__ __launch_bounds__(1024) void kA(
    const float* __restrict__ hiddens, float* __restrict__ newh,
    float* __restrict__ ws)
{
    __shared__ char  wlds[98304];       // W1L @0 (64KB), W2L @65536 (32KB)
    __shared__ char  hsb[64 * 256];     // bf16 [64][128] swizzled (16KB)
    __shared__ char  agb[64 * 512];     // bf16 [64][256] (32KB)
    __shared__ float ts_s[64];
    __shared__ float tsum_s[64];

    const int t    = threadIdx.x;
    const int lane = t & 63;
    const int w    = t >> 6;
    const int rg   = w >> 2;
    const int nq   = w & 3;
    const int col  = lane & 15;
    const int kq   = lane >> 4;
    const int r0   = rg * 16;
    const int n0   = blockIdx.x * 64;

    {
        const float4* src = (const float4*)(ws + WS_FRAG);
        float4* dst = (float4*)wlds;
#pragma unroll
        for (int p = 0; p < 6; p++) dst[p * 1024 + t] = src[p * 1024 + t];
    }
    const short8* W1F = (const short8*)wlds;
    const short8* W2F = (const short8*)(wlds + 65536);

    const float bo = ws[WS_BOUT + nq * 16 + col];
    float co_reg[4];
#pragma unroll
    for (int i = 0; i < 4; i++) co_reg[i] = 0.f;
    if (t < 64) tsum_s[t] = 0.f;

    const int flat = t * 8;
    const int srow = flat >> 7;
    const int scb  = (flat & 127) * 2;

    {
        const float* hs = hiddens + (size_t)n0 * HID;
        float4 a0 = *(const float4*)(hs + flat);
        float4 a1 = *(const float4*)(hs + flat + 4);
        stg(hsb, srow, scb, a0, a1);
    }
    float4 pfa0, pfa1;
    unsigned short* outu = (unsigned short*)newh;

    for (int b = 0; b < NB; ++b) {
        __syncthreads();  // bar0
        if (t < 64) {
            if (b > 0) {
                ws[WS_TS + (size_t)(b - 1) * NCC + n0 + t] = ts_s[t];
                tsum_s[t] += ts_s[t];
            }
            ts_s[t] = 0.f;
        }
        if (b < 7) {
            const float* hsn = hiddens + ((size_t)((b + 1) * NCC + n0)) * HID;
            pfa0 = *(const float4*)(hsn + flat);
            pfa1 = *(const float4*)(hsn + flat + 4);
        }

        // ---- L1 ----
        {
            short8 aH[4];
#pragma unroll
            for (int ks = 0; ks < 4; ks++) {
                int row = r0 + col;
                aH[ks] = *(const short8*)(hsb + row * 256 +
                           ((ks * 64 + (kq << 4)) ^ ((row & 7) << 4)));
            }
#pragma unroll
            for (int nti = 0; nti < 4; nti++) {
                int nt = nq * 4 + nti;
                f32x4 ac = {0.f, 0.f, 0.f, 0.f};
#pragma unroll
                for (int kt = 0; kt < 4; kt++)
                    ac = MFMA(aH[kt], W1F[(nt * 4 + kt) * 64 + lane], ac);
                int n = nt * 16 + col;
                float bs = ws[WS_BASE1 + b * 256 + n];
#pragma unroll
                for (int j = 0; j < 4; j++) {
                    int row = r0 + (kq << 2) + j;
                    float v = fmaxf(ac[j] + bs, 0.f);
                    *(unsigned short*)(agb + row * 512 +
                        ((n * 2) ^ ((row & 7) << 4))) = f2b(v);
                }
            }
        }
        __syncthreads();  // barA

        if (b < 7) stg(hsb, srow, scb, pfa0, pfa1);

        // ---- L2 ----
        {
            f32x4 ov = {0.f, 0.f, 0.f, 0.f};
#pragma unroll
            for (int kt = 0; kt < 8; kt++) {
                int kb = kt * 64 + (kq << 4);
                int ra = r0 + col;
                short8 a0 = *(const short8*)(agb + ra * 512 + (kb ^ ((ra & 7) << 4)));
                ov = MFMA(a0, W2F[(nq * 8 + kt) * 64 + lane], ov);
            }
            int d = nq * 16 + col;
            float aab = ws[WS_AABS + b];
#pragma unroll
            for (int j = 0; j < 4; j++) {
                int row = r0 + (kq << 2) + j;
                float v = ov[j] + bo;
                co_reg[j] += aab * v;
                outu[(size_t)(b * NCC + n0 + row) * 256 + 192 + d] = f2b(v);
                float sq = v * v;
                sq += __shfl_xor(sq, 1);
                sq += __shfl_xor(sq, 2);
                sq += __shfl_xor(sq, 4);
                sq += __shfl_xor(sq, 8);
                if (col == 0) atomicAdd(&ts_s[row], sq);
            }
        }
    }
    __syncthreads();
    if (t < 64) {
        ws[WS_TS + (size_t)7 * NCC + n0 + t] = ts_s[t];
        tsum_s[t] += ts_s[t];
        ws[WS_AVGT + n0 + t] = tsum_s[t] * (1.f / 512.f);
    }
    {
        int d = nq * 16 + col;
#pragma unroll
        for (int j = 0; j < 4; j++) {
            int row = r0 + (kq << 2) + j;
            ws[WS_CO + (size_t)(n0 + row) * 64 + d] = co_reg[j];
        }
    }
}

// ================= kB: GRU, 256 blocks x 64 cells, single pass ==============
// 1024 thr (16 waves: rg(2) x hg(8)); WHH (96KB) in LDS; WIH slice in REGISTERS.
__global__ __launch_bounds__(1024) void kB(
    const float* __restrict__ hiddens, float* __restrict__ newh,
    float* __restrict__ ws)
{
    __shared__ char  wl[98304];         // WHH (96KB)
    __shared__ char  hsb[64 * 256];     // bf16 [64][128] swizzled (16KB)
    __shared__ char  otb[64 * 128];     // bf16 [64][64]  swizzled (8KB)
    __shared__ float ts_s[64];
    __shared__ float fp2[2][128];

    const int t    = threadIdx.x;
    const int lane = t & 63;
    const int w    = t >> 6;            // 0..15
    const int rg   = w >> 3;            // 0..1 -> rows rg*32..+32
    const int hg   = w & 7;             // 0..7
    const int col  = lane & 15;
    const int kq   = lane >> 4;
    const int chunk = blockIdx.x;       // 256 chunks of 64 cells
    const int n0   = chunk * 64;

    // stage WHH: 96KB = 6144 float4 (frag byte offset 147456 = float4 idx 9216)
    {
        const float4* src = (const float4*)(ws + WS_FRAG) + 9216;
        float4* dst = (float4*)wl;
#pragma unroll
        for (int p = 0; p < 6; p++) dst[p * 1024 + t] = src[p * 1024 + t];
    }
    const short8* WHHF = (const short8*)wl;
    const unsigned short* outu = (const unsigned short*)newh;

    // WIH slice for this wave's hg: branch-invariant -> registers (6 short8)
    const short8* WIHG = (const short8*)((const short*)(ws + WS_FRAG) + 49152);
    short8 wihR[2], wihZ[2], wihI[2];
#pragma unroll
    for (int ks = 0; ks < 2; ks++) {
        wihR[ks] = WIHG[(hg * 2 + ks) * 64 + lane];
        wihZ[ks] = WIHG[((hg + 8) * 2 + ks) * 64 + lane];
        wihI[ks] = WIHG[((hg + 16) * 2 + ks) * 64 + lane];
    }

    const int h = hg * 16 + col;
    const float bsr = ws[WS_BSUMR + h];
    const float bsz = ws[WS_BSUMZ + h];
    const float bin = ws[WS_BIHN + h];
    const float bhn = ws[WS_BHHN + h];
    const float wr  = ws[WS_W64 + h];
    const float wz  = ws[WS_W64 + 128 + h];
    const float wn  = ws[WS_W64 + 256 + h];

    const int flat = t * 8;             // 8192 floats = 64x128
    const int srow = flat >> 7;
    const int scb  = (flat & 127) * 2;
    const int ocell = t >> 4;           // 0..63
    const int ooff  = (t & 15) * 4;     // u16 offset 0..60

    // prologue: load branch 0 tiles into regs
    float4 rh0, rh1;
    uint2  ro;
    float  rts = 0.f;
    {
        const float* hs = hiddens + (size_t)n0 * HID;
        rh0 = *(const float4*)(hs + flat);
        rh1 = *(const float4*)(hs + flat + 4);
        ro  = *(const uint2*)(outu + (size_t)(n0 + ocell) * 256 + 192 + ooff);
    }
    if (t < 64) rts = ws[WS_TS + n0 + t];

    for (int b = 0; b < NB; ++b) {
        stg(hsb, srow, scb, rh0, rh1);
        *(uint2*)(otb + ocell * 128 + ((ooff * 2) ^ ((ocell & 7) << 4))) = ro;
        if (t < 64) ts_s[t] = rts;
        __syncthreads();  // bar0: tiles ready

        if (b < 7) {
            const float* hsn = hiddens + ((size_t)((b + 1) * NCC + n0)) * HID;
            rh0 = *(const float4*)(hsn + flat);
            rh1 = *(const float4*)(hsn + flat + 4);
            ro  = *(const uint2*)(outu + (size_t)((b + 1) * NCC + n0 + ocell) * 256 + 192 + ooff);
            if (t < 64) rts = ws[WS_TS + (size_t)(b + 1) * NCC + n0 + t];
        }

        // ---- GRU: 2 row-tiles per wave; gi from regs, gh from LDS ----
        {
            float* nbase = newh + ((size_t)(b * NCC + n0)) * HID;
            float flsum = 0.f;
#pragma unroll
            for (int st = 0; st < 2; ++st) {
                const int rbase = rg * 32 + st * 16;
                const int ra = rbase + col;
                f32x4 R = {0.f,0.f,0.f,0.f};
                f32x4 Z = {0.f,0.f,0.f,0.f};
                f32x4 I = {0.f,0.f,0.f,0.f};
                f32x4 N = {0.f,0.f,0.f,0.f};
#pragma unroll
                for (int ks = 0; ks < 2; ks++) {
                    short8 a0 = *(const short8*)(otb + ra * 128 +
                                 ((ks * 64 + (kq << 4)) ^ ((ra & 7) << 4)));
                    R = MFMA(a0, wihR[ks], R);
                    Z = MFMA(a0, wihZ[ks], Z);
                    I = MFMA(a0, wihI[ks], I);
                }
#pragma unroll
                for (int ks = 0; ks < 4; ks++) {
                    short8 a0 = *(const short8*)(hsb + ra * 256 +
                                 ((ks * 64 + (kq << 4)) ^ ((ra & 7) << 4)));
                    R = MFMA(a0, WHHF[(hg * 4 + ks) * 64 + lane], R);
                    Z = MFMA(a0, WHHF[((hg + 8) * 4 + ks) * 64 + lane], Z);
                    N = MFMA(a0, WHHF[((hg + 16) * 4 + ks) * 64 + lane], N);
                }
#pragma unroll
                for (int j = 0; j < 4; j++) {
                    int row = rbase + (kq << 2) + j;
                    float tv = ts_s[row] * (1.f / 64.f);
                    float r  = sigm(R[j] + bsr + tv * wr);
                    float z  = sigm(Z[j] + bsz + tv * wz);
                    float hn = N[j] + bhn;
                    float nn = tanh_fast(I[j] + bin + tv * wn + r * hn);
                    float hold = b2f(*(const unsigned short*)(hsb + row * 256 +
                                     ((h * 2) ^ ((row & 7) << 4))));
                    float nh = (1.f - z) * nn + z * hold;
                    nbase[(size_t)row * HID + h] = nh;
                    flsum += nh;
                }
            }
            flsum += __shfl_xor(flsum, 16);
            flsum += __shfl_xor(flsum, 32);
            if (kq == 0) fp2[rg][h] = flsum;   // unique writer per (rg,h)
        }
        __syncthreads();  // barC: tile reads + fp2 done

        if (t < 128)
            ws[WS_FPART + ((size_t)(b * 256 + chunk)) * 128 + t] = fp2[0][t] + fp2[1][t];
    }
}

// ---------------- merged: kred (blocks 0-255) + fmean (blocks 256-319) -----
__global__ __launch_bounds__(256) void kfr(float* __restrict__ ws)
{
    int blk = blockIdx.x, t = threadIdx.x;
    if (blk < 256) {
        __shared__ float wexp[64];
        __shared__ float red[256];
        int n0 = blk * 64;
        float av = 0.f;
        if (t < 64) {
            av = ws[WS_AVGT + n0 + t];
            wexp[t] = __expf(av);
        }
        __syncthreads();
        int d = t & 63, q = t >> 6;
        float s = 0.f;
        for (int i = 0; i < 16; i++) {
            int c = q * 16 + i;
            s += wexp[c] * ws[WS_CO + (size_t)(n0 + c) * 64 + d];
        }
        red[t] = s; __syncthreads();
        if (t < 64)
            ws[WS_PART2 + blk * 64 + t] = red[t] + red[64 + t] + red[128 + t] + red[192 + t];
        if (t < 64) {
            float e = wexp[t], a2 = av;
            e  += __shfl_xor(e, 1);  a2 += __shfl_xor(a2, 1);
            e  += __shfl_xor(e, 2);  a2 += __shfl_xor(a2, 2);
            e  += __shfl_xor(e, 4);  a2 += __shfl_xor(a2, 4);
            e  += __shfl_xor(e, 8);  a2 += __shfl_xor(a2, 8);
            e  += __shfl_xor(e, 16); a2 += __shfl_xor(a2, 16);
            e  += __shfl_xor(e, 32); a2 += __shfl_xor(a2, 32);
            if (t == 0) { ws[WS_PARTE + blk] = e; ws[WS_PARTA + blk] = a2; }
        }
    } else {
        // fmean over 256 chunks of 64 cells
        int bf = blk - 256;
        int b = bf >> 3, f = bf & 7;
        if (t < 128) {
            int h = t;
            float s = 0.f, s8 = 0.f;
            for (int j = 0; j < 32; j++) {
                float v = ws[WS_FPART + ((size_t)(b * 256 + f * 32 + j)) * 128 + h];
                s += v;
                if (j < 8) s8 += v;    // first 512 cells
            }
            ws[WS_FMEAN + (b * 8 + f) * 128 + h] = s * (1.f / 2048.f);
            ws[WS_SD + (b * 8 + f) * 128 + h] = s8;
        }
    }
}

// ---------------- merged: k4mv (blocks 0-127) + kpred (block 128) ----------
__global__ __launch_bounds__(256) void kmp(
    const float* __restrict__ mixW, const float* __restrict__ mixb,
    const float* __restrict__ headW, const float* __restrict__ headb,
    const int* __restrict__ step, float* __restrict__ ws,
    float* __restrict__ d_out)
{
    int blk = blockIdx.x, t = threadIdx.x;
    if (blk < 128) {
        __shared__ float hm[1024];
        __shared__ float red[256];
        bool deb = (step[0] > 5);
        for (int j = t; j < 1024; j += 256) {
            int b = j >> 7, hh = j & 127;
            float s = 0.f, sd = 0.f;
            for (int f = 0; f < 8; f++) {
                s  += ws[WS_FMEAN + (b * 8 + f) * 128 + hh];
                sd += ws[WS_SD + (b * 8 + f) * 128 + hh];
            }
            float gl = s * 0.125f;
            float tot = 16384.f * gl;
            if (deb) tot += 0.15f * (3481.6f * gl - 0.85f * sd);
            hm[j] = tot * (1.f / 16384.f);
        }
        __syncthreads();
        float4 wv = *(const float4*)(mixW + (size_t)blk * 1024 + t * 4);
        float4 hv = *(const float4*)(&hm[t * 4]);
        float s = wv.x * hv.x + wv.y * hv.y + wv.z * hv.z + wv.w * hv.w;
        red[t] = s; __syncthreads();
        for (int st = 128; st > 0; st >>= 1) { if (t < st) red[t] += red[t + st]; __syncthreads(); }
        if (t == 0) ws[WS_INTERF + blk] = mixb[blk] + red[0];
    } else {
        __shared__ float red[256];
        __shared__ float num[64];
        __shared__ float den_s;
        int d = t & 63, q = t >> 6;
        float s = 0.f;
        for (int i = 0; i < 64; i++) s += ws[WS_PART2 + (q * 64 + i) * 64 + d];
        red[t] = s; __syncthreads();
        if (t < 64) num[t] = red[t] + red[64 + t] + red[128 + t] + red[192 + t];
        __syncthreads();
        red[t] = ws[WS_PARTE + t]; __syncthreads();
        for (int st = 128; st > 0; st >>= 1) { if (t < st) red[t] += red[t + st]; __syncthreads(); }
        if (t == 0) den_s = red[0];
        __syncthreads();
        red[t] = ws[WS_PARTA + t]; __syncthreads();
        for (int st = 128; st > 0; st >>= 1) { if (t < st) red[t] += red[t + st]; __syncthreads(); }
        if (t == 0) d_out[64] = red[0] * (1.f / (float)NCC);
        __syncthreads();
        if (t < 64) {
            float inv_den = 1.f / den_s;
            float p = headb[t];
            for (int d2 = 0; d2 < 64; d2++) p += (num[d2] * inv_den) * headW[t * 64 + d2];
            d_out[t] = p;
        }
    }
}

// ---------------- fused sync/debate blend + interf apply (float4) ---------
__global__ __launch_bounds__(256) void k35_blend(
    float* __restrict__ newh, const float* __restrict__ ws,
    const int* __restrict__ step)
{
    int blk = blockIdx.x;              // 2048 = 8 * 256
    int b = blk >> 8, ck = blk & 255;
    int t = threadIdx.x;
    int h4 = t & 31;
    int cg = t >> 5;
    int base = ck * 64;
    int f = base >> 11;
    bool deb = (step[0] > 5) && ((base & 2047) < 512);
    float4 fm = *(const float4*)(ws + WS_FMEAN + (size_t)(b * 8 + f) * 128 + h4 * 4);
    float glx = 0.f, gly = 0.f, glz = 0.f, glw = 0.f;
    for (int ff = 0; ff < 8; ff++) {
        float4 v = *(const float4*)(ws + WS_FMEAN + (size_t)(b * 8 + ff) * 128 + h4 * 4);
        glx += v.x; gly += v.y; glz += v.z; glw += v.w;
    }
    glx *= 0.125f; gly *= 0.125f; glz *= 0.125f; glw *= 0.125f;
    float4 itf = {0.f, 0.f, 0.f, 0.f};
    if (b == 0) {
        float4 iv = *(const float4*)(ws + WS_INTERF + h4 * 4);
        itf.x = 0.05f * iv.x; itf.y = 0.05f * iv.y;
        itf.z = 0.05f * iv.z; itf.w = 0.05f * iv.w;
    }
    for (int i = 0; i < 8; i++) {
        int cell = base + i * 8 + cg;
        size_t idx = ((size_t)b * NCC + cell) * 128 + h4 * 4;
        float4 v = *(float4*)(newh + idx);
        v.x = 0.85f * v.x + 0.15f * fm.x;
        v.y = 0.85f * v.y + 0.15f * fm.y;
        v.z = 0.85f * v.z + 0.15f * fm.z;
        v.w = 0.85f * v.w + 0.15f * fm.w;
        if (deb) {
            v.x = 0.85f * v.x + 0.15f * glx;
            v.y = 0.85f * v.y + 0.15f * gly;
            v.z = 0.85f * v.z + 0.15f * glz;
            v.w = 0.85f * v.w + 0.15f * glw;
        }
        v.x += itf.x; v.y += itf.y; v.z += itf.z; v.w += itf.w;
        *(float4*)(newh + idx) = v;
    }
}

extern "C" void kernel_launch(void* const* d_in, const int* in_sizes, int n_in,
                              void* d_out, int out_size, void* d_ws, size_t ws_size,
                              hipStream_t stream)
{
    const float* x       = (const float*)d_in[0];
    const float* noise   = (const float*)d_in[1];
    const float* amps    = (const float*)d_in[2];
    const float* hiddens = (const float*)d_in[3];
    const float* eaW1    = (const float*)d_in[4];
    const float* eaB1    = (const float*)d_in[5];
    const float* eaW2    = (const float*)d_in[6];
    const float* eaB2    = (const float*)d_in[7];
    const float* egW1    = (const float*)d_in[8];
    const float* egB1    = (const float*)d_in[9];
    const float* egW2    = (const float*)d_in[10];
    const float* egB2    = (const float*)d_in[11];
    const float* gWih    = (const float*)d_in[12];
    const float* gWhh    = (const float*)d_in[13];
    const float* gbih    = (const float*)d_in[14];
    const float* gbhh    = (const float*)d_in[15];
    const float* headW   = (const float*)d_in[16];
    const float* headb   = (const float*)d_in[17];
    const float* mixW    = (const float*)d_in[18];
    const float* mixb    = (const float*)d_in[19];
    const int*   step    = (const int*)d_in[20];

    float* out  = (float*)d_out;
    float* newh = out + 65;   // [pred(64), avg_t_mean(1), newh(8*16384*128)]
    float* ws   = (float*)d_ws;

    kprep<<<120, 1024, 0, stream>>>(x, noise, amps, eaW1, eaB1, egW1, egB1,
                                    eaW2, eaB2, egW2, egB2, gWih, gWhh,
                                    gbih, gbhh, ws);
    kA<<<256, 1024, 0, stream>>>(hiddens, newh, ws);
    kB<<<256, 1024, 0, stream>>>(hiddens, newh, ws);
    kfr<<<320, 256, 0, stream>>>(ws);
    kmp<<<129, 256, 0, stream>>>(mixW, mixb, headW, headb, step, ws, out);
    k35_blend<<<2048, 256, 0, stream>>>(newh, ws, step);
}